// Round 11
// baseline (94.702 us; speedup 1.0000x reference)
//
#include <hip/hip_runtime.h>
#include <hip/hip_bf16.h>
#include <stdint.h>

#define N_NODES 50000
#define KNB 32
#define DIM 256

typedef short s8v __attribute__((ext_vector_type(8)));
typedef float f4v __attribute__((ext_vector_type(4)));
typedef float f2v __attribute__((ext_vector_type(2)));
typedef int i4v __attribute__((ext_vector_type(4)));
typedef int i2v __attribute__((ext_vector_type(2)));
typedef unsigned short u16;
typedef unsigned char u8;

__device__ inline float bf2f(u16 h) {
    unsigned int u = ((unsigned int)h) << 16;
    return __builtin_bit_cast(float, u);
}
__device__ inline u16 f2bf(float f) {
    unsigned int u = __builtin_bit_cast(unsigned int, f);
    unsigned int r = (u + 0x7fffu + ((u >> 16) & 1u)) >> 16;
    return (u16)r;
}

// ---- OCP e4m3 encode/decode: hw cvt when available, exact bit-trick otherwise
__device__ inline unsigned fp8_enc1_manual(float f) {
    unsigned fb = __builtin_bit_cast(unsigned, f);
    unsigned s = (fb >> 24) & 0x80u;
    float a = fminf(fabsf(f), 448.0f);
    unsigned u = __builtin_bit_cast(unsigned, a * 0x1p-120f);
    unsigned r = (u + 0x7ffffu + ((u >> 20) & 1u)) >> 20;   // RNE to 3-bit mant
    return s | r;
}

template <bool HI>
__device__ inline unsigned fp8_enc_pair(float f0, float f1, unsigned old) {
#if __has_builtin(__builtin_amdgcn_cvt_pk_fp8_f32)
    return (unsigned)__builtin_amdgcn_cvt_pk_fp8_f32(f0, f1, (int)old, HI);
#else
    unsigned half = fp8_enc1_manual(f0) | (fp8_enc1_manual(f1) << 8);
    return HI ? ((old & 0x0000ffffu) | (half << 16))
              : ((old & 0xffff0000u) | half);
#endif
}

template <bool HI>
__device__ inline f2v fp8_dec_pair(unsigned w) {
#if __has_builtin(__builtin_amdgcn_cvt_pk_f32_fp8)
    return __builtin_amdgcn_cvt_pk_f32_fp8(w, HI);
#else
    unsigned h0 = (w >> (HI ? 16 : 0)) & 0xffu;
    unsigned h1 = (w >> (HI ? 24 : 8)) & 0xffu;
    f2v r;
    r[0] = __builtin_bit_cast(float, ((h0 & 0x80u) << 24) | ((h0 & 0x7fu) << 20)) * 0x1p+120f;
    r[1] = __builtin_bit_cast(float, ((h1 & 0x80u) << 24) | ((h1 & 0x7fu) << 20)) * 0x1p+120f;
    return r;
#endif
}

#define GLOAD16(gp, lp) __builtin_amdgcn_global_load_lds( \
    (const __attribute__((address_space(1))) unsigned int*)(gp), \
    (__attribute__((address_space(3))) unsigned int*)(lp), 16, 0, 0)

// Layouts:
//  xbs[c8][n][32] bf16, c8 in [0,8)  — GEMM A operand (3.2 MB/chunk)
//  xq [c4][n][64] fp8,  c4 in [0,4)  — gather source: 64B row = ONE cache line
//  sbs[c8][n][32] bf16               — gather output (GEMM A, K=256..511)

// ---- kernel 1: convert x -> {bf16 sliced, fp8 sliced}, weights^T, esc ------
__global__ __launch_bounds__(256) void k_convert(
    const float* __restrict__ x, const float* __restrict__ Wc,
    const float* __restrict__ Wn, const float* __restrict__ edge,
    const int* __restrict__ adj, u16* __restrict__ xbs, u8* __restrict__ xq,
    u16* __restrict__ Wct, u16* __restrict__ Wnt, float* __restrict__ esc,
    u16* __restrict__ adj16, float* __restrict__ invv)
{
    int64_t tid = (int64_t)blockIdx.x * blockDim.x + threadIdx.x;
    int64_t stride = (int64_t)gridDim.x * blockDim.x;

    // item i = (n, d16): 16 dims -> 2x s8v bf16 + 1x i4v fp8
    const int64_t nitems = (int64_t)N_NODES * 16;
    for (int64_t i = tid; i < nitems; i += stride) {
        int n = (int)(i >> 4), d16 = (int)(i & 15);
        const float4* xp = (const float4*)(x + (int64_t)n * 256 + d16 * 16);
        float4 t0 = xp[0], t1 = xp[1], t2 = xp[2], t3 = xp[3];
        float v[16] = {t0.x, t0.y, t0.z, t0.w, t1.x, t1.y, t1.z, t1.w,
                       t2.x, t2.y, t2.z, t2.w, t3.x, t3.y, t3.z, t3.w};
        u16* bp = xbs + ((int64_t)(d16 >> 1) * N_NODES + n) * 32 + (d16 & 1) * 16;
        s8v b0, b1;
        #pragma unroll
        for (int j = 0; j < 8; ++j) {
            b0[j] = (short)f2bf(v[j]);
            b1[j] = (short)f2bf(v[j + 8]);
        }
        *(s8v*)bp = b0;
        *(s8v*)(bp + 8) = b1;

        unsigned q0, q1, q2, q3;
        q0 = fp8_enc_pair<false>(v[0], v[1], 0);   q0 = fp8_enc_pair<true>(v[2], v[3], q0);
        q1 = fp8_enc_pair<false>(v[4], v[5], 0);   q1 = fp8_enc_pair<true>(v[6], v[7], q1);
        q2 = fp8_enc_pair<false>(v[8], v[9], 0);   q2 = fp8_enc_pair<true>(v[10], v[11], q2);
        q3 = fp8_enc_pair<false>(v[12], v[13], 0); q3 = fp8_enc_pair<true>(v[14], v[15], q3);
        u8* qp = xq + ((int64_t)(d16 >> 2) * N_NODES + n) * 64 + (d16 & 3) * 16;
        i4v qv = {(int)q0, (int)q1, (int)q2, (int)q3};
        *(i4v*)qp = qv;
    }

    // weights -> bf16 transposed [col][k]
    for (int64_t i = tid; i < 256 * 256; i += stride) {
        int r = (int)(i >> 8), c = (int)(i & 255);   // W[r][c]
        Wct[c * 256 + r] = f2bf(Wc[i]);
        Wnt[c * 256 + r] = f2bf(Wn[i]);
    }

    // per-node: esc = inv*sum_k edge, adj16 = wrapped u16 adj, invv = 1/nh
    int lane = threadIdx.x & 63;
    int gw = (int)((blockIdx.x * 256 + threadIdx.x) >> 6);
    int nwaves = (int)((gridDim.x * 256) >> 6);
    for (int n = gw; n < N_NODES; n += nwaves) {
        float ev = edge[(int64_t)n * 64 + lane];
        ev += __shfl_xor(ev, 2);
        ev += __shfl_xor(ev, 4);
        ev += __shfl_xor(ev, 8);
        ev += __shfl_xor(ev, 16);
        ev += __shfl_xor(ev, 32);
        int a = (lane < 32) ? adj[n * 32 + lane] : 0;
        unsigned long long m = __ballot(lane < 32 && a != -1);
        float inv = 1.0f / fmaxf((float)__popcll(m), 1.0f);
        if (lane < 32) {
            int w = a < 0 ? a + N_NODES : a;   // numpy wrap for -1 padding
            adj16[n * 32 + lane] = (u16)w;
        }
        if (lane < 2) esc[n * 2 + lane] = ev * inv;
        if (lane == 0) invv[n] = inv;
    }
}

// ---- kernel 2: fp8 gather-sum, 8 nodes/wave x 8B/lane (max concurrency) ----
__global__ __launch_bounds__(256) void k_gather(
    const u8* __restrict__ xq, const u16* __restrict__ adj16,
    const float* __restrict__ invv, u16* __restrict__ sbs)
{
    int wv = threadIdx.x >> 6, lane = threadIdx.x & 63;
    int c = blockIdx.x & 3;                  // chunk -> XCD pair {c, c+4}
    int n0 = (int)(blockIdx.x >> 2) * 32 + wv * 8;
    if (n0 >= N_NODES) return;
    int node = lane >> 3, seg = lane & 7;
    int n = n0 + node;
    int nc = n < N_NODES ? n : N_NODES - 1;

    // preload this wave's 256 adj entries: lane holds (node=lane>>3, k=(lane&7)*4+j)
    int64_t aoff = (int64_t)n0 * 32 + lane * 4;
    i2v aw = *(const i2v*)(adj16 + aoff);
    int a[4];
    a[0] = aw[0] & 0xffff; a[1] = (int)(((unsigned)aw[0]) >> 16);
    a[2] = aw[1] & 0xffff; a[3] = (int)(((unsigned)aw[1]) >> 16);

    float iv = invv[nc];
    const u8* base = xq + (int64_t)c * N_NODES * 64 + seg * 8;

    float acc[8] = {0.f, 0.f, 0.f, 0.f, 0.f, 0.f, 0.f, 0.f};
    #pragma unroll
    for (int k = 0; k < 32; ++k) {
        int src = (lane & 56) | (k >> 2);        // node-base | k-group lane
        int idx = __shfl(a[k & 3], src);         // a[k&3]: static index
        i2v w = *(const i2v*)(base + (int64_t)idx * 64);
        #pragma unroll
        for (int r = 0; r < 2; ++r) {
            f2v lo = fp8_dec_pair<false>((unsigned)w[r]);
            f2v hi = fp8_dec_pair<true>((unsigned)w[r]);
            acc[r * 4 + 0] += lo[0];
            acc[r * 4 + 1] += lo[1];
            acc[r * 4 + 2] += hi[0];
            acc[r * 4 + 3] += hi[1];
        }
    }

    if (n < N_NODES) {
        int c8 = c * 2 + (seg >> 2);
        u16* sp = sbs + ((int64_t)c8 * N_NODES + n) * 32 + (seg & 3) * 8;
        s8v o;
        #pragma unroll
        for (int j = 0; j < 8; ++j) o[j] = (short)f2bf(acc[j] * iv);
        *(s8v*)sp = o;
    }
}

// ---- kernel 3: K=512 bf16 MFMA GEMM, BK=32, 3-buffer counted-vmcnt ring ----
// Per-thread stage of one tile = 4 global_load_lds (2 A + 2 B).
// Ring schedule per iter t: vmcnt(4) [tile t's loads retired, t+1's in
// flight] -> s_barrier -> issue stage(t+2) -> ds_read/MFMA tile t.
// Overwrite of buf[(t+2)%3] is barrier-ordered after all reads of tile t-1.
__device__ inline void stage_A32(u16* tile, const u16* src, int row0,
                                 int chunk, int wv, int lane)
{
    #pragma unroll
    for (int cc = 0; cc < 2; ++cc) {
        int idxbase = cc * 256 + wv * 64;      // wave-uniform LDS base
        int idx = idxbase + lane;
        int row = idx >> 2, seg = idx & 3;
        int gr = row0 + row; if (gr >= N_NODES) gr = N_NODES - 1;
        int srcseg = seg ^ ((row ^ (row >> 2)) & 3);
        const u16* g = src + ((int64_t)chunk * N_NODES + gr) * 32 + srcseg * 8;
        GLOAD16(g, (char*)tile + idxbase * 16);
    }
}
__device__ inline void stage_B32(u16* tile, const u16* src, int col0,
                                 int kofsEl, int wv, int lane)
{
    #pragma unroll
    for (int cc = 0; cc < 2; ++cc) {
        int idxbase = cc * 256 + wv * 64;
        int idx = idxbase + lane;
        int row = idx >> 2, seg = idx & 3;
        int srcseg = seg ^ ((row ^ (row >> 2)) & 3);
        const u16* g = src + (int64_t)(col0 + row) * 256 + kofsEl + srcseg * 8;
        GLOAD16(g, (char*)tile + idxbase * 16);
    }
}

__global__ __launch_bounds__(256, 3) void k_gemm(
    const u16* __restrict__ xbs, const u16* __restrict__ sbs,
    const u16* __restrict__ Wct, const u16* __restrict__ Wnt,
    const float* __restrict__ esc, const float* __restrict__ We,
    const float* __restrict__ bias, float* __restrict__ out)
{
    __shared__ u16 Atile[3][128 * 32];
    __shared__ u16 Btile[3][128 * 32];

    int wv = threadIdx.x >> 6, lane = threadIdx.x & 63;
    int wm = wv >> 1, wn = wv & 1;

    // bijective XCD-chunked swizzle (m204): contiguous logical range per XCD,
    // so the two N-tiles sharing an A-panel run on the SAME XCD back-to-back.
    int nwg = gridDim.x;
    int xcd = blockIdx.x & 7, lo = blockIdx.x >> 3;
    int q = nwg >> 3, r = nwg & 7;
    int bid = (xcd < r ? xcd * (q + 1) : r * (q + 1) + (xcd - r) * q) + lo;

    int bm = bid >> 1;                 // M-tile (391)
    int nt = bid & 1;                  // N-tile (2)
    int mrow0 = bm * 128;
    int ncol0 = nt * 128;

    f4v acc[4][4];
    #pragma unroll
    for (int m = 0; m < 4; ++m)
        #pragma unroll
        for (int n = 0; n < 4; ++n) acc[m][n] = (f4v){0.f, 0.f, 0.f, 0.f};

    // prologue: stage tiles 0 and 1 (8 loads/thread outstanding)
    stage_A32(Atile[0], xbs, mrow0, 0, wv, lane);
    stage_B32(Btile[0], Wct, ncol0, 0, wv, lane);
    stage_A32(Atile[1], xbs, mrow0, 1, wv, lane);
    stage_B32(Btile[1], Wct, ncol0, 32, wv, lane);

    int lrow = wm * 64, lcol = wn * 64;
    int l15 = lane & 15, l4 = lane >> 4;

    #pragma unroll
    for (int kb = 0; kb < 16; ++kb) {
        if (kb < 15) {
            asm volatile("s_waitcnt vmcnt(4)" ::: "memory");
        } else {
            asm volatile("s_waitcnt vmcnt(0)" ::: "memory");
        }
        __builtin_amdgcn_s_barrier();
        if (kb < 14) {
            int kn = kb + 2;
            const u16* As = (kn < 8) ? xbs : sbs;
            const u16* Bs = (kn < 8) ? Wct : Wnt;
            stage_A32(Atile[(kb + 2) % 3], As, mrow0, kn & 7, wv, lane);
            stage_B32(Btile[(kb + 2) % 3], Bs, ncol0, (kn & 7) * 32, wv, lane);
        }
        const u16* At = Atile[kb % 3];
        const u16* Bt = Btile[kb % 3];
        s8v af[4], bfr[4];
        #pragma unroll
        for (int m = 0; m < 4; ++m) {
            int row = lrow + m * 16 + l15;
            int sg = (l4 ^ ((row ^ (row >> 2)) & 3)) * 16;
            af[m] = *(const s8v*)((const char*)At + row * 64 + sg);
        }
        #pragma unroll
        for (int n = 0; n < 4; ++n) {
            int col = lcol + n * 16 + l15;
            int sg = (l4 ^ ((col ^ (col >> 2)) & 3)) * 16;
            bfr[n] = *(const s8v*)((const char*)Bt + col * 64 + sg);
        }
        #pragma unroll
        for (int m = 0; m < 4; ++m)
            #pragma unroll
            for (int n = 0; n < 4; ++n)
                acc[m][n] = __builtin_amdgcn_mfma_f32_16x16x32_bf16(
                    af[m], bfr[n], acc[m][n], 0, 0, 0);
    }

    // epilogue: C/D layout col=lane&15, row=(lane>>4)*4+reg
    #pragma unroll
    for (int m = 0; m < 4; ++m) {
        int r0 = mrow0 + lrow + m * 16 + l4 * 4;
        float e0[4], e1[4];
        #pragma unroll
        for (int r2 = 0; r2 < 4; ++r2) {
            int row = r0 + r2; if (row >= N_NODES) row = N_NODES - 1;
            e0[r2] = esc[row * 2];
            e1[r2] = esc[row * 2 + 1];
        }
        #pragma unroll
        for (int n = 0; n < 4; ++n) {
            int col = ncol0 + lcol + n * 16 + l15;
            float bc = bias[col];
            float w0 = We[col];
            float w1 = We[256 + col];
            #pragma unroll
            for (int r2 = 0; r2 < 4; ++r2) {
                int row = r0 + r2;
                if (row < N_NODES) {
                    float v = acc[m][n][r2] + bc + e0[r2] * w0 + e1[r2] * w1;
                    out[(int64_t)row * 256 + col] = fmaxf(v, 0.0f);
                }
            }
        }
    }
}

extern "C" void kernel_launch(void* const* d_in, const int* in_sizes, int n_in,
                              void* d_out, int out_size, void* d_ws, size_t ws_size,
                              hipStream_t stream) {
    const float* x    = (const float*)d_in[0];
    const int*   adj  = (const int*)d_in[1];
    const float* edge = (const float*)d_in[2];
    const float* Wc   = (const float*)d_in[3];
    const float* Wn   = (const float*)d_in[4];
    const float* We   = (const float*)d_in[5];
    // d_in[6] = q : dead (softmax over size-1 axis == 1.0)
    const float* bias = (const float*)d_in[7];
    float* out = (float*)d_out;

    char* ws = (char*)d_ws;
    u16*   xbs   = (u16*)(ws);                   // 8*N*32 bf16 = 25.6 MB
    u16*   sbs   = (u16*)(ws + 25600000);        // 8*N*32 bf16 = 25.6 MB
    float* esc   = (float*)(ws + 51200000);      // N*2 f32     = 0.4 MB
    u16*   Wct   = (u16*)(ws + 51600000);        // 128 KB
    u16*   Wnt   = (u16*)(ws + 51731072);        // 128 KB
    u16*   adj16 = (u16*)(ws + 51862144);        // N*32 u16    = 3.2 MB
    float* invv  = (float*)(ws + 55062144);      // N f32       = 0.2 MB
    u8*    xq    = (u8*)(ws + 55262144);         // 4*N*64 fp8  = 12.8 MB

    k_convert<<<2048, 256, 0, stream>>>(x, Wc, Wn, edge, adj, xbs, xq, Wct, Wnt,
                                        esc, adj16, invv);
    k_gather<<<((N_NODES + 31) / 32) * 4, 256, 0, stream>>>(xq, adj16, invv, sbs);
    k_gemm<<<(N_NODES + 127) / 128 * 2, 256, 0, stream>>>(xbs, sbs, Wct, Wnt, esc, We, bias, out);
}

// Round 12
// 92.087 us; speedup vs baseline: 1.0284x; 1.0284x over previous
//
#include <hip/hip_runtime.h>
#include <hip/hip_bf16.h>
#include <stdint.h>

#define N_NODES 50000
#define KNB 32
#define DIM 256

typedef short s8v __attribute__((ext_vector_type(8)));
typedef float f4v __attribute__((ext_vector_type(4)));
typedef float f2v __attribute__((ext_vector_type(2)));
typedef int i4v __attribute__((ext_vector_type(4)));
typedef int i2v __attribute__((ext_vector_type(2)));
typedef unsigned short u16;
typedef unsigned char u8;

__device__ inline float bf2f(u16 h) {
    unsigned int u = ((unsigned int)h) << 16;
    return __builtin_bit_cast(float, u);
}
__device__ inline u16 f2bf(float f) {
    unsigned int u = __builtin_bit_cast(unsigned int, f);
    unsigned int r = (u + 0x7fffu + ((u >> 16) & 1u)) >> 16;
    return (u16)r;
}

// ---- OCP e4m3 encode/decode: hw cvt when available, exact bit-trick otherwise
__device__ inline unsigned fp8_enc1_manual(float f) {
    unsigned fb = __builtin_bit_cast(unsigned, f);
    unsigned s = (fb >> 24) & 0x80u;
    float a = fminf(fabsf(f), 448.0f);
    unsigned u = __builtin_bit_cast(unsigned, a * 0x1p-120f);
    unsigned r = (u + 0x7ffffu + ((u >> 20) & 1u)) >> 20;   // RNE to 3-bit mant
    return s | r;
}

template <bool HI>
__device__ inline unsigned fp8_enc_pair(float f0, float f1, unsigned old) {
#if __has_builtin(__builtin_amdgcn_cvt_pk_fp8_f32)
    return (unsigned)__builtin_amdgcn_cvt_pk_fp8_f32(f0, f1, (int)old, HI);
#else
    unsigned half = fp8_enc1_manual(f0) | (fp8_enc1_manual(f1) << 8);
    return HI ? ((old & 0x0000ffffu) | (half << 16))
              : ((old & 0xffff0000u) | half);
#endif
}

template <bool HI>
__device__ inline f2v fp8_dec_pair(unsigned w) {
#if __has_builtin(__builtin_amdgcn_cvt_pk_f32_fp8)
    return __builtin_amdgcn_cvt_pk_f32_fp8(w, HI);
#else
    unsigned h0 = (w >> (HI ? 16 : 0)) & 0xffu;
    unsigned h1 = (w >> (HI ? 24 : 8)) & 0xffu;
    f2v r;
    r[0] = __builtin_bit_cast(float, ((h0 & 0x80u) << 24) | ((h0 & 0x7fu) << 20)) * 0x1p+120f;
    r[1] = __builtin_bit_cast(float, ((h1 & 0x80u) << 24) | ((h1 & 0x7fu) << 20)) * 0x1p+120f;
    return r;
#endif
}

#define GLOAD16(gp, lp) __builtin_amdgcn_global_load_lds( \
    (const __attribute__((address_space(1))) unsigned int*)(gp), \
    (__attribute__((address_space(3))) unsigned int*)(lp), 16, 0, 0)

// Layouts:
//  xbs[c8][n][32] bf16, c8 in [0,8)  — GEMM A operand (3.2 MB/chunk)
//  xq [c4][n][64] fp8,  c4 in [0,4)  — gather source: 64B row = ONE cache line
//  sbs[c8][n][32] bf16               — gather output (GEMM A, K=256..511)

// ---- kernel 1: convert x -> {bf16 sliced, fp8 sliced}, weights^T, esc ------
__global__ __launch_bounds__(256) void k_convert(
    const float* __restrict__ x, const float* __restrict__ Wc,
    const float* __restrict__ Wn, const float* __restrict__ edge,
    const int* __restrict__ adj, u16* __restrict__ xbs, u8* __restrict__ xq,
    u16* __restrict__ Wct, u16* __restrict__ Wnt, float* __restrict__ esc,
    u16* __restrict__ adj16, float* __restrict__ invv)
{
    int64_t tid = (int64_t)blockIdx.x * blockDim.x + threadIdx.x;
    int64_t stride = (int64_t)gridDim.x * blockDim.x;

    // item i = (n, d16): 16 dims -> 2x s8v bf16 + 1x i4v fp8
    const int64_t nitems = (int64_t)N_NODES * 16;
    for (int64_t i = tid; i < nitems; i += stride) {
        int n = (int)(i >> 4), d16 = (int)(i & 15);
        const float4* xp = (const float4*)(x + (int64_t)n * 256 + d16 * 16);
        float4 t0 = xp[0], t1 = xp[1], t2 = xp[2], t3 = xp[3];
        float v[16] = {t0.x, t0.y, t0.z, t0.w, t1.x, t1.y, t1.z, t1.w,
                       t2.x, t2.y, t2.z, t2.w, t3.x, t3.y, t3.z, t3.w};
        u16* bp = xbs + ((int64_t)(d16 >> 1) * N_NODES + n) * 32 + (d16 & 1) * 16;
        s8v b0, b1;
        #pragma unroll
        for (int j = 0; j < 8; ++j) {
            b0[j] = (short)f2bf(v[j]);
            b1[j] = (short)f2bf(v[j + 8]);
        }
        *(s8v*)bp = b0;
        *(s8v*)(bp + 8) = b1;

        unsigned q0, q1, q2, q3;
        q0 = fp8_enc_pair<false>(v[0], v[1], 0);   q0 = fp8_enc_pair<true>(v[2], v[3], q0);
        q1 = fp8_enc_pair<false>(v[4], v[5], 0);   q1 = fp8_enc_pair<true>(v[6], v[7], q1);
        q2 = fp8_enc_pair<false>(v[8], v[9], 0);   q2 = fp8_enc_pair<true>(v[10], v[11], q2);
        q3 = fp8_enc_pair<false>(v[12], v[13], 0); q3 = fp8_enc_pair<true>(v[14], v[15], q3);
        u8* qp = xq + ((int64_t)(d16 >> 2) * N_NODES + n) * 64 + (d16 & 3) * 16;
        i4v qv = {(int)q0, (int)q1, (int)q2, (int)q3};
        *(i4v*)qp = qv;
    }

    // weights -> bf16 transposed [col][k]
    for (int64_t i = tid; i < 256 * 256; i += stride) {
        int r = (int)(i >> 8), c = (int)(i & 255);   // W[r][c]
        Wct[c * 256 + r] = f2bf(Wc[i]);
        Wnt[c * 256 + r] = f2bf(Wn[i]);
    }

    // per-node: esc = inv*sum_k edge, adj16 = wrapped u16 adj, invv = 1/nh
    int lane = threadIdx.x & 63;
    int gw = (int)((blockIdx.x * 256 + threadIdx.x) >> 6);
    int nwaves = (int)((gridDim.x * 256) >> 6);
    for (int n = gw; n < N_NODES; n += nwaves) {
        float ev = edge[(int64_t)n * 64 + lane];
        ev += __shfl_xor(ev, 2);
        ev += __shfl_xor(ev, 4);
        ev += __shfl_xor(ev, 8);
        ev += __shfl_xor(ev, 16);
        ev += __shfl_xor(ev, 32);
        int a = (lane < 32) ? adj[n * 32 + lane] : 0;
        unsigned long long m = __ballot(lane < 32 && a != -1);
        float inv = 1.0f / fmaxf((float)__popcll(m), 1.0f);
        if (lane < 32) {
            int w = a < 0 ? a + N_NODES : a;   // numpy wrap for -1 padding
            adj16[n * 32 + lane] = (u16)w;
        }
        if (lane < 2) esc[n * 2 + lane] = ev * inv;
        if (lane == 0) invv[n] = inv;
    }
}

// ---- kernel 2: fp8 gather-sum, 8 nodes/wave x 8B/lane (max concurrency) ----
__global__ __launch_bounds__(256) void k_gather(
    const u8* __restrict__ xq, const u16* __restrict__ adj16,
    const float* __restrict__ invv, u16* __restrict__ sbs)
{
    int wv = threadIdx.x >> 6, lane = threadIdx.x & 63;
    int c = blockIdx.x & 3;                  // chunk -> XCD pair {c, c+4}
    int n0 = (int)(blockIdx.x >> 2) * 32 + wv * 8;
    if (n0 >= N_NODES) return;
    int node = lane >> 3, seg = lane & 7;
    int n = n0 + node;
    int nc = n < N_NODES ? n : N_NODES - 1;

    // preload this wave's 256 adj entries: lane holds (node=lane>>3, k=(lane&7)*4+j)
    int64_t aoff = (int64_t)n0 * 32 + lane * 4;
    i2v aw = *(const i2v*)(adj16 + aoff);
    int a[4];
    a[0] = aw[0] & 0xffff; a[1] = (int)(((unsigned)aw[0]) >> 16);
    a[2] = aw[1] & 0xffff; a[3] = (int)(((unsigned)aw[1]) >> 16);

    float iv = invv[nc];
    const u8* base = xq + (int64_t)c * N_NODES * 64 + seg * 8;

    float acc[8] = {0.f, 0.f, 0.f, 0.f, 0.f, 0.f, 0.f, 0.f};
    #pragma unroll
    for (int k = 0; k < 32; ++k) {
        int src = (lane & 56) | (k >> 2);        // node-base | k-group lane
        int idx = __shfl(a[k & 3], src);         // a[k&3]: static index
        i2v w = *(const i2v*)(base + (int64_t)idx * 64);
        #pragma unroll
        for (int r = 0; r < 2; ++r) {
            f2v lo = fp8_dec_pair<false>((unsigned)w[r]);
            f2v hi = fp8_dec_pair<true>((unsigned)w[r]);
            acc[r * 4 + 0] += lo[0];
            acc[r * 4 + 1] += lo[1];
            acc[r * 4 + 2] += hi[0];
            acc[r * 4 + 3] += hi[1];
        }
    }

    if (n < N_NODES) {
        int c8 = c * 2 + (seg >> 2);
        u16* sp = sbs + ((int64_t)c8 * N_NODES + n) * 32 + (seg & 3) * 8;
        s8v o;
        #pragma unroll
        for (int j = 0; j < 8; ++j) o[j] = (short)f2bf(acc[j] * iv);
        *(s8v*)sp = o;
    }
}

// ---- kernel 3: K=512 bf16 MFMA GEMM, BM=64 BN=128 BK=32, 6 blocks/CU -------
// R10's proven compiler-managed 2-buffer loop (__syncthreads), smaller M-tile
// for occupancy: LDS 24KB -> 6 blocks/CU, 24 waves/CU hide the barrier drain.
__device__ inline void stage_A64(u16* tile, const u16* src, int row0,
                                 int chunk, int tix)
{
    // 64 rows x 4 segs = 256 loads; one per thread
    int row = tix >> 2, seg = tix & 3;
    int gr = row0 + row; if (gr >= N_NODES) gr = N_NODES - 1;
    int srcseg = seg ^ ((row ^ (row >> 2)) & 3);
    const u16* g = src + ((int64_t)chunk * N_NODES + gr) * 32 + srcseg * 8;
    GLOAD16(g, (char*)tile + ((tix & ~63)) * 16 + (tix & 63) * 16);
}
__device__ inline void stage_B128(u16* tile, const u16* src, int col0,
                                  int kofsEl, int wv, int lane)
{
    #pragma unroll
    for (int cc = 0; cc < 2; ++cc) {
        int idxbase = cc * 256 + wv * 64;
        int idx = idxbase + lane;
        int row = idx >> 2, seg = idx & 3;
        int srcseg = seg ^ ((row ^ (row >> 2)) & 3);
        const u16* g = src + (int64_t)(col0 + row) * 256 + kofsEl + srcseg * 8;
        GLOAD16(g, (char*)tile + idxbase * 16);
    }
}

__global__ __launch_bounds__(256, 6) void k_gemm(
    const u16* __restrict__ xbs, const u16* __restrict__ sbs,
    const u16* __restrict__ Wct, const u16* __restrict__ Wnt,
    const float* __restrict__ esc, const float* __restrict__ We,
    const float* __restrict__ bias, float* __restrict__ out)
{
    __shared__ u16 Atile[2][64 * 32];
    __shared__ u16 Btile[2][128 * 32];

    int wv = threadIdx.x >> 6, lane = threadIdx.x & 63;
    int tix = threadIdx.x;

    // bijective XCD-chunked swizzle (m204)
    int nwg = gridDim.x;
    int xcd = blockIdx.x & 7, lo = blockIdx.x >> 3;
    int q = nwg >> 3, r = nwg & 7;
    int bid = (xcd < r ? xcd * (q + 1) : r * (q + 1) + (xcd - r) * q) + lo;

    int bm = bid >> 1;                 // M-tile (782)
    int nt = bid & 1;                  // N-tile (2)
    int mrow0 = bm * 64;
    int ncol0 = nt * 128;

    f4v acc[4][2];
    #pragma unroll
    for (int m = 0; m < 4; ++m)
        #pragma unroll
        for (int n = 0; n < 2; ++n) acc[m][n] = (f4v){0.f, 0.f, 0.f, 0.f};

    stage_A64(Atile[0], xbs, mrow0, 0, tix);
    stage_B128(Btile[0], Wct, ncol0, 0, wv, lane);
    __syncthreads();

    int cur = 0;
    int lcol = wv * 32;                // wave covers 32 cols x 64 rows
    int l15 = lane & 15, l4 = lane >> 4;

    for (int kb = 0; kb < 16; ++kb) {
        if (kb < 15) {
            int kn = kb + 1;
            const u16* As = (kn < 8) ? xbs : sbs;
            const u16* Bs = (kn < 8) ? Wct : Wnt;
            stage_A64(Atile[cur ^ 1], As, mrow0, kn & 7, tix);
            stage_B128(Btile[cur ^ 1], Bs, ncol0, (kn & 7) * 32, wv, lane);
        }
        const u16* At = Atile[cur];
        const u16* Bt = Btile[cur];
        s8v af[4], bfr[2];
        #pragma unroll
        for (int m = 0; m < 4; ++m) {
            int row = m * 16 + l15;
            int sg = (l4 ^ ((row ^ (row >> 2)) & 3)) * 16;
            af[m] = *(const s8v*)((const char*)At + row * 64 + sg);
        }
        #pragma unroll
        for (int n = 0; n < 2; ++n) {
            int col = lcol + n * 16 + l15;
            int sg = (l4 ^ ((col ^ (col >> 2)) & 3)) * 16;
            bfr[n] = *(const s8v*)((const char*)Bt + col * 64 + sg);
        }
        #pragma unroll
        for (int m = 0; m < 4; ++m)
            #pragma unroll
            for (int n = 0; n < 2; ++n)
                acc[m][n] = __builtin_amdgcn_mfma_f32_16x16x32_bf16(
                    af[m], bfr[n], acc[m][n], 0, 0, 0);
        __syncthreads();
        cur ^= 1;
    }

    // epilogue: C/D layout col=lane&15, row=(lane>>4)*4+reg
    #pragma unroll
    for (int m = 0; m < 4; ++m) {
        int r0 = mrow0 + m * 16 + l4 * 4;
        float e0[4], e1[4];
        #pragma unroll
        for (int r2 = 0; r2 < 4; ++r2) {
            int row = r0 + r2; if (row >= N_NODES) row = N_NODES - 1;
            e0[r2] = esc[row * 2];
            e1[r2] = esc[row * 2 + 1];
        }
        #pragma unroll
        for (int n = 0; n < 2; ++n) {
            int col = ncol0 + lcol + n * 16 + l15;
            float bc = bias[col];
            float w0 = We[col];
            float w1 = We[256 + col];
            #pragma unroll
            for (int r2 = 0; r2 < 4; ++r2) {
                int row = r0 + r2;
                if (row < N_NODES) {
                    float v = acc[m][n][r2] + bc + e0[r2] * w0 + e1[r2] * w1;
                    out[(int64_t)row * 256 + col] = fmaxf(v, 0.0f);
                }
            }
        }
    }
}

extern "C" void kernel_launch(void* const* d_in, const int* in_sizes, int n_in,
                              void* d_out, int out_size, void* d_ws, size_t ws_size,
                              hipStream_t stream) {
    const float* x    = (const float*)d_in[0];
    const int*   adj  = (const int*)d_in[1];
    const float* edge = (const float*)d_in[2];
    const float* Wc   = (const float*)d_in[3];
    const float* Wn   = (const float*)d_in[4];
    const float* We   = (const float*)d_in[5];
    // d_in[6] = q : dead (softmax over size-1 axis == 1.0)
    const float* bias = (const float*)d_in[7];
    float* out = (float*)d_out;

    char* ws = (char*)d_ws;
    u16*   xbs   = (u16*)(ws);                   // 8*N*32 bf16 = 25.6 MB
    u16*   sbs   = (u16*)(ws + 25600000);        // 8*N*32 bf16 = 25.6 MB
    float* esc   = (float*)(ws + 51200000);      // N*2 f32     = 0.4 MB
    u16*   Wct   = (u16*)(ws + 51600000);        // 128 KB
    u16*   Wnt   = (u16*)(ws + 51731072);        // 128 KB
    u16*   adj16 = (u16*)(ws + 51862144);        // N*32 u16    = 3.2 MB
    float* invv  = (float*)(ws + 55062144);      // N f32       = 0.2 MB
    u8*    xq    = (u8*)(ws + 55262144);         // 4*N*64 fp8  = 12.8 MB

    k_convert<<<2048, 256, 0, stream>>>(x, Wc, Wn, edge, adj, xbs, xq, Wct, Wnt,
                                        esc, adj16, invv);
    k_gather<<<((N_NODES + 31) / 32) * 4, 256, 0, stream>>>(xq, adj16, invv, sbs);
    k_gemm<<<((N_NODES + 63) / 64) * 2, 256, 0, stream>>>(xbs, sbs, Wct, Wnt, esc, We, bias, out);
}

// Round 13
// 87.382 us; speedup vs baseline: 1.0838x; 1.0538x over previous
//
#include <hip/hip_runtime.h>
#include <hip/hip_bf16.h>
#include <stdint.h>

#define N_NODES 50000
#define KNB 32
#define DIM 256

typedef short s8v __attribute__((ext_vector_type(8)));
typedef float f4v __attribute__((ext_vector_type(4)));
typedef float f2v __attribute__((ext_vector_type(2)));
typedef int i4v __attribute__((ext_vector_type(4)));
typedef int i2v __attribute__((ext_vector_type(2)));
typedef unsigned short u16;
typedef unsigned char u8;

__device__ inline float bf2f(u16 h) {
    unsigned int u = ((unsigned int)h) << 16;
    return __builtin_bit_cast(float, u);
}
__device__ inline u16 f2bf(float f) {
    unsigned int u = __builtin_bit_cast(unsigned int, f);
    unsigned int r = (u + 0x7fffu + ((u >> 16) & 1u)) >> 16;
    return (u16)r;
}

// ---- OCP e4m3 encode/decode: hw cvt when available, exact bit-trick otherwise
__device__ inline unsigned fp8_enc1_manual(float f) {
    unsigned fb = __builtin_bit_cast(unsigned, f);
    unsigned s = (fb >> 24) & 0x80u;
    float a = fminf(fabsf(f), 448.0f);
    unsigned u = __builtin_bit_cast(unsigned, a * 0x1p-120f);
    unsigned r = (u + 0x7ffffu + ((u >> 20) & 1u)) >> 20;   // RNE to 3-bit mant
    return s | r;
}

template <bool HI>
__device__ inline unsigned fp8_enc_pair(float f0, float f1, unsigned old) {
#if __has_builtin(__builtin_amdgcn_cvt_pk_fp8_f32)
    return (unsigned)__builtin_amdgcn_cvt_pk_fp8_f32(f0, f1, (int)old, HI);
#else
    unsigned half = fp8_enc1_manual(f0) | (fp8_enc1_manual(f1) << 8);
    return HI ? ((old & 0x0000ffffu) | (half << 16))
              : ((old & 0xffff0000u) | half);
#endif
}

template <bool HI>
__device__ inline f2v fp8_dec_pair(unsigned w) {
#if __has_builtin(__builtin_amdgcn_cvt_pk_f32_fp8)
    return __builtin_amdgcn_cvt_pk_f32_fp8(w, HI);
#else
    unsigned h0 = (w >> (HI ? 16 : 0)) & 0xffu;
    unsigned h1 = (w >> (HI ? 24 : 8)) & 0xffu;
    f2v r;
    r[0] = __builtin_bit_cast(float, ((h0 & 0x80u) << 24) | ((h0 & 0x7fu) << 20)) * 0x1p+120f;
    r[1] = __builtin_bit_cast(float, ((h1 & 0x80u) << 24) | ((h1 & 0x7fu) << 20)) * 0x1p+120f;
    return r;
#endif
}

#define GLOAD16(gp, lp) __builtin_amdgcn_global_load_lds( \
    (const __attribute__((address_space(1))) unsigned int*)(gp), \
    (__attribute__((address_space(3))) unsigned int*)(lp), 16, 0, 0)

// Layouts:
//  xbs[c8][n][32] bf16, c8 in [0,8)  — GEMM A operand (3.2 MB/chunk)
//  xq [c4][n][64] fp8,  c4 in [0,4)  — gather source: 64B row = ONE cache line
//  sbs[c8][n][32] bf16               — gather output (GEMM A, K=256..511)

// ---- kernel 1: convert x -> {bf16 sliced, fp8 sliced}, weights^T, esc ------
__global__ __launch_bounds__(256) void k_convert(
    const float* __restrict__ x, const float* __restrict__ Wc,
    const float* __restrict__ Wn, const float* __restrict__ edge,
    const int* __restrict__ adj, u16* __restrict__ xbs, u8* __restrict__ xq,
    u16* __restrict__ Wct, u16* __restrict__ Wnt, float* __restrict__ esc,
    u16* __restrict__ adj16, float* __restrict__ invv)
{
    int64_t tid = (int64_t)blockIdx.x * blockDim.x + threadIdx.x;
    int64_t stride = (int64_t)gridDim.x * blockDim.x;

    // item i = (n, d16): 16 dims -> 2x s8v bf16 + 1x i4v fp8
    const int64_t nitems = (int64_t)N_NODES * 16;
    for (int64_t i = tid; i < nitems; i += stride) {
        int n = (int)(i >> 4), d16 = (int)(i & 15);
        const float4* xp = (const float4*)(x + (int64_t)n * 256 + d16 * 16);
        float4 t0 = xp[0], t1 = xp[1], t2 = xp[2], t3 = xp[3];
        float v[16] = {t0.x, t0.y, t0.z, t0.w, t1.x, t1.y, t1.z, t1.w,
                       t2.x, t2.y, t2.z, t2.w, t3.x, t3.y, t3.z, t3.w};
        u16* bp = xbs + ((int64_t)(d16 >> 1) * N_NODES + n) * 32 + (d16 & 1) * 16;
        s8v b0, b1;
        #pragma unroll
        for (int j = 0; j < 8; ++j) {
            b0[j] = (short)f2bf(v[j]);
            b1[j] = (short)f2bf(v[j + 8]);
        }
        *(s8v*)bp = b0;
        *(s8v*)(bp + 8) = b1;

        unsigned q0, q1, q2, q3;
        q0 = fp8_enc_pair<false>(v[0], v[1], 0);   q0 = fp8_enc_pair<true>(v[2], v[3], q0);
        q1 = fp8_enc_pair<false>(v[4], v[5], 0);   q1 = fp8_enc_pair<true>(v[6], v[7], q1);
        q2 = fp8_enc_pair<false>(v[8], v[9], 0);   q2 = fp8_enc_pair<true>(v[10], v[11], q2);
        q3 = fp8_enc_pair<false>(v[12], v[13], 0); q3 = fp8_enc_pair<true>(v[14], v[15], q3);
        u8* qp = xq + ((int64_t)(d16 >> 2) * N_NODES + n) * 64 + (d16 & 3) * 16;
        i4v qv = {(int)q0, (int)q1, (int)q2, (int)q3};
        *(i4v*)qp = qv;
    }

    // weights -> bf16 transposed [col][k]
    for (int64_t i = tid; i < 256 * 256; i += stride) {
        int r = (int)(i >> 8), c = (int)(i & 255);   // W[r][c]
        Wct[c * 256 + r] = f2bf(Wc[i]);
        Wnt[c * 256 + r] = f2bf(Wn[i]);
    }

    // per-node: esc = inv*sum_k edge, adj16 = wrapped u16 adj, invv = 1/nh
    int lane = threadIdx.x & 63;
    int gw = (int)((blockIdx.x * 256 + threadIdx.x) >> 6);
    int nwaves = (int)((gridDim.x * 256) >> 6);
    for (int n = gw; n < N_NODES; n += nwaves) {
        float ev = edge[(int64_t)n * 64 + lane];
        ev += __shfl_xor(ev, 2);
        ev += __shfl_xor(ev, 4);
        ev += __shfl_xor(ev, 8);
        ev += __shfl_xor(ev, 16);
        ev += __shfl_xor(ev, 32);
        int a = (lane < 32) ? adj[n * 32 + lane] : 0;
        unsigned long long m = __ballot(lane < 32 && a != -1);
        float inv = 1.0f / fmaxf((float)__popcll(m), 1.0f);
        if (lane < 32) {
            int w = a < 0 ? a + N_NODES : a;   // numpy wrap for -1 padding
            adj16[n * 32 + lane] = (u16)w;
        }
        if (lane < 2) esc[n * 2 + lane] = ev * inv;
        if (lane == 0) invv[n] = inv;
    }
}

// ---- kernel 2: fp8 gather-sum, 8 nodes/wave x 8B/lane (max concurrency) ----
// lane: node=lane>>3, seg=lane&7 (8 fp8 dims). 8 lanes cover one 64B line.
__global__ __launch_bounds__(256) void k_gather(
    const u8* __restrict__ xq, const u16* __restrict__ adj16,
    const float* __restrict__ invv, u16* __restrict__ sbs)
{
    int wv = threadIdx.x >> 6, lane = threadIdx.x & 63;
    int c = blockIdx.x & 3;                  // chunk -> XCD pair {c, c+4}
    int n0 = (int)(blockIdx.x >> 2) * 32 + wv * 8;
    if (n0 >= N_NODES) return;
    int node = lane >> 3, seg = lane & 7;
    int n = n0 + node;
    int nc = n < N_NODES ? n : N_NODES - 1;

    // preload this wave's 256 adj entries: lane holds (node=lane>>3, k=(lane&7)*4+j)
    int64_t aoff = (int64_t)n0 * 32 + lane * 4;
    i2v aw = *(const i2v*)(adj16 + aoff);
    int a[4];
    a[0] = aw[0] & 0xffff; a[1] = (int)(((unsigned)aw[0]) >> 16);
    a[2] = aw[1] & 0xffff; a[3] = (int)(((unsigned)aw[1]) >> 16);

    float iv = invv[nc];
    const u8* base = xq + (int64_t)c * N_NODES * 64 + seg * 8;

    float acc[8] = {0.f, 0.f, 0.f, 0.f, 0.f, 0.f, 0.f, 0.f};
    #pragma unroll
    for (int k = 0; k < 32; ++k) {
        int src = (lane & 56) | (k >> 2);        // node-base | k-group lane
        int idx = __shfl(a[k & 3], src);         // a[k&3]: static index
        i2v w = *(const i2v*)(base + (int64_t)idx * 64);
        #pragma unroll
        for (int r = 0; r < 2; ++r) {
            f2v lo = fp8_dec_pair<false>((unsigned)w[r]);
            f2v hi = fp8_dec_pair<true>((unsigned)w[r]);
            acc[r * 4 + 0] += lo[0];
            acc[r * 4 + 1] += lo[1];
            acc[r * 4 + 2] += hi[0];
            acc[r * 4 + 3] += hi[1];
        }
    }

    if (n < N_NODES) {
        int c8 = c * 2 + (seg >> 2);
        u16* sp = sbs + ((int64_t)c8 * N_NODES + n) * 32 + (seg & 3) * 8;
        s8v o;
        #pragma unroll
        for (int j = 0; j < 8; ++j) o[j] = (short)f2bf(acc[j] * iv);
        *(s8v*)sp = o;
    }
}

// ---- kernel 3: LDS-staged K=512 bf16 MFMA GEMM, BK=32, XCD-swizzled --------
__device__ inline void stage_A32(u16* tile, const u16* src, int row0,
                                 int chunk, int wv, int lane)
{
    #pragma unroll
    for (int cc = 0; cc < 2; ++cc) {
        int idxbase = cc * 256 + wv * 64;      // wave-uniform LDS base
        int idx = idxbase + lane;
        int row = idx >> 2, seg = idx & 3;
        int gr = row0 + row; if (gr >= N_NODES) gr = N_NODES - 1;
        int srcseg = seg ^ ((row ^ (row >> 2)) & 3);
        const u16* g = src + ((int64_t)chunk * N_NODES + gr) * 32 + srcseg * 8;
        GLOAD16(g, (char*)tile + idxbase * 16);
    }
}
__device__ inline void stage_B32(u16* tile, const u16* src, int col0,
                                 int kofsEl, int wv, int lane)
{
    #pragma unroll
    for (int cc = 0; cc < 2; ++cc) {
        int idxbase = cc * 256 + wv * 64;
        int idx = idxbase + lane;
        int row = idx >> 2, seg = idx & 3;
        int srcseg = seg ^ ((row ^ (row >> 2)) & 3);
        const u16* g = src + (int64_t)(col0 + row) * 256 + kofsEl + srcseg * 8;
        GLOAD16(g, (char*)tile + idxbase * 16);
    }
}

__global__ __launch_bounds__(256, 4) void k_gemm(
    const u16* __restrict__ xbs, const u16* __restrict__ sbs,
    const u16* __restrict__ Wct, const u16* __restrict__ Wnt,
    const float* __restrict__ esc, const float* __restrict__ We,
    const float* __restrict__ bias, float* __restrict__ out)
{
    __shared__ u16 Atile[2][128 * 32];
    __shared__ u16 Btile[2][128 * 32];

    int wv = threadIdx.x >> 6, lane = threadIdx.x & 63;
    int wm = wv >> 1, wn = wv & 1;

    // bijective XCD-chunked swizzle (m204): contiguous logical range per XCD,
    // so the two N-tiles sharing an A-panel run on the SAME XCD back-to-back.
    int nwg = gridDim.x;
    int xcd = blockIdx.x & 7, lo = blockIdx.x >> 3;
    int q = nwg >> 3, r = nwg & 7;
    int bid = (xcd < r ? xcd * (q + 1) : r * (q + 1) + (xcd - r) * q) + lo;

    int bm = bid >> 1;                 // M-tile (391)
    int nt = bid & 1;                  // N-tile (2)
    int mrow0 = bm * 128;
    int ncol0 = nt * 128;

    f4v acc[4][4];
    #pragma unroll
    for (int m = 0; m < 4; ++m)
        #pragma unroll
        for (int n = 0; n < 4; ++n) acc[m][n] = (f4v){0.f, 0.f, 0.f, 0.f};

    stage_A32(Atile[0], xbs, mrow0, 0, wv, lane);
    stage_B32(Btile[0], Wct, ncol0, 0, wv, lane);
    __syncthreads();

    int cur = 0;
    int lrow = wm * 64, lcol = wn * 64;
    int l15 = lane & 15, l4 = lane >> 4;

    for (int kb = 0; kb < 16; ++kb) {
        if (kb < 15) {
            int kn = kb + 1;
            const u16* As = (kn < 8) ? xbs : sbs;
            const u16* Bs = (kn < 8) ? Wct : Wnt;
            stage_A32(Atile[cur ^ 1], As, mrow0, kn & 7, wv, lane);
            stage_B32(Btile[cur ^ 1], Bs, ncol0, (kn & 7) * 32, wv, lane);
        }
        const u16* At = Atile[cur];
        const u16* Bt = Btile[cur];
        s8v af[4], bfr[4];
        #pragma unroll
        for (int m = 0; m < 4; ++m) {
            int row = lrow + m * 16 + l15;
            int sg = (l4 ^ ((row ^ (row >> 2)) & 3)) * 16;
            af[m] = *(const s8v*)((const char*)At + row * 64 + sg);
        }
        #pragma unroll
        for (int n = 0; n < 4; ++n) {
            int col = lcol + n * 16 + l15;
            int sg = (l4 ^ ((col ^ (col >> 2)) & 3)) * 16;
            bfr[n] = *(const s8v*)((const char*)Bt + col * 64 + sg);
        }
        #pragma unroll
        for (int m = 0; m < 4; ++m)
            #pragma unroll
            for (int n = 0; n < 4; ++n)
                acc[m][n] = __builtin_amdgcn_mfma_f32_16x16x32_bf16(
                    af[m], bfr[n], acc[m][n], 0, 0, 0);
        __syncthreads();
        cur ^= 1;
    }

    // epilogue: C/D layout col=lane&15, row=(lane>>4)*4+reg
    #pragma unroll
    for (int m = 0; m < 4; ++m) {
        int r0 = mrow0 + lrow + m * 16 + l4 * 4;
        float e0[4], e1[4];
        #pragma unroll
        for (int r2 = 0; r2 < 4; ++r2) {
            int row = r0 + r2; if (row >= N_NODES) row = N_NODES - 1;
            e0[r2] = esc[row * 2];
            e1[r2] = esc[row * 2 + 1];
        }
        #pragma unroll
        for (int n = 0; n < 4; ++n) {
            int col = ncol0 + lcol + n * 16 + l15;
            float bc = bias[col];
            float w0 = We[col];
            float w1 = We[256 + col];
            #pragma unroll
            for (int r2 = 0; r2 < 4; ++r2) {
                int row = r0 + r2;
                if (row < N_NODES) {
                    float v = acc[m][n][r2] + bc + e0[r2] * w0 + e1[r2] * w1;
                    out[(int64_t)row * 256 + col] = fmaxf(v, 0.0f);
                }
            }
        }
    }
}

extern "C" void kernel_launch(void* const* d_in, const int* in_sizes, int n_in,
                              void* d_out, int out_size, void* d_ws, size_t ws_size,
                              hipStream_t stream) {
    const float* x    = (const float*)d_in[0];
    const int*   adj  = (const int*)d_in[1];
    const float* edge = (const float*)d_in[2];
    const float* Wc   = (const float*)d_in[3];
    const float* Wn   = (const float*)d_in[4];
    const float* We   = (const float*)d_in[5];
    // d_in[6] = q : dead (softmax over size-1 axis == 1.0)
    const float* bias = (const float*)d_in[7];
    float* out = (float*)d_out;

    char* ws = (char*)d_ws;
    u16*   xbs   = (u16*)(ws);                   // 8*N*32 bf16 = 25.6 MB
    u16*   sbs   = (u16*)(ws + 25600000);        // 8*N*32 bf16 = 25.6 MB
    float* esc   = (float*)(ws + 51200000);      // N*2 f32     = 0.4 MB
    u16*   Wct   = (u16*)(ws + 51600000);        // 128 KB
    u16*   Wnt   = (u16*)(ws + 51731072);        // 128 KB
    u16*   adj16 = (u16*)(ws + 51862144);        // N*32 u16    = 3.2 MB
    float* invv  = (float*)(ws + 55062144);      // N f32       = 0.2 MB
    u8*    xq    = (u8*)(ws + 55262144);         // 4*N*64 fp8  = 12.8 MB

    k_convert<<<2048, 256, 0, stream>>>(x, Wc, Wn, edge, adj, xbs, xq, Wct, Wnt,
                                        esc, adj16, invv);
    k_gather<<<((N_NODES + 31) / 32) * 4, 256, 0, stream>>>(xq, adj16, invv, sbs);
    k_gemm<<<(N_NODES + 127) / 128 * 2, 256, 0, stream>>>(xbs, sbs, Wct, Wnt, esc, We, bias, out);
}